// Round 2
// baseline (988.004 us; speedup 1.0000x reference)
//
#include <hip/hip_runtime.h>

typedef unsigned short u16;
typedef unsigned int u32;
typedef __attribute__((ext_vector_type(8))) short short8;
typedef __attribute__((ext_vector_type(4))) float floatx4;

// ---- bf16 <-> f32 helpers (raw bits, RNE) ----
__device__ __forceinline__ float bf2f(u16 u) {
    u32 x = ((u32)u) << 16;
    float f;
    __builtin_memcpy(&f, &x, 4);
    return f;
}
__device__ __forceinline__ u16 f2bf(float f) {
    u32 x;
    __builtin_memcpy(&x, &f, 4);
    u32 r = (x + 0x7fffu + ((x >> 16) & 1u)) >> 16;
    return (u16)r;
}

// ==========================================================================
// Convert f32 -> bf16, 4 elems/thread (n must be divisible by 4*256)
// ==========================================================================
__global__ __launch_bounds__(256) void convert_x(const float* __restrict__ in,
                                                 u16* __restrict__ out, int n4) {
    int i = blockIdx.x * 256 + threadIdx.x;
    float4 v = *(const float4*)(in + (size_t)i * 4);
    u16 o[4] = {f2bf(v.x), f2bf(v.y), f2bf(v.z), f2bf(v.w)};
    *(ulong1*)(out + (size_t)i * 4) = *(ulong1*)o;
}

// ==========================================================================
// Convert + transpose: in f32 (R x C) -> out bf16 (C x R)
// ==========================================================================
__global__ __launch_bounds__(1024) void transpose_wc(const float* __restrict__ in,
                                                     u16* __restrict__ out,
                                                     int R, int C) {
    __shared__ u16 t[32][33];
    const int tx = threadIdx.x, ty = threadIdx.y;
    const int c0 = blockIdx.x * 32, r0 = blockIdx.y * 32;
    t[ty][tx] = f2bf(in[(size_t)(r0 + ty) * C + c0 + tx]);
    __syncthreads();
    out[(size_t)(c0 + ty) * R + r0 + tx] = t[tx][ty];
}

// V (b,s,kv,d) bf16 -> Vt (b,kv,d,s);  B=2,S=2048,NKV=8,D=128
__global__ __launch_bounds__(1024) void transpose_v(const u16* __restrict__ V,
                                                    u16* __restrict__ Vt) {
    __shared__ u16 t[32][33];
    const int tx = threadIdx.x, ty = threadIdx.y;
    const int b = blockIdx.z >> 3, kv = blockIdx.z & 7;
    const int s0 = blockIdx.x * 32, d0 = blockIdx.y * 32;
    t[ty][tx] = V[(size_t)b * 2097152 + (size_t)(s0 + ty) * 1024 + kv * 128 + d0 + tx];
    __syncthreads();
    Vt[(size_t)b * 2097152 + (size_t)kv * 262144 + (size_t)(d0 + ty) * 2048 + s0 + tx] = t[tx][ty];
}

// ==========================================================================
// GEMM: C[M,N] = A[M,K] @ Bt[N,K]^T   (bf16 in, fp32 acc, OUT_T out)
// tile 128x128, BK=64, 256 threads (4 waves, 2x2 of 64x64)
// ==========================================================================
template <typename OUT_T>
__global__ __launch_bounds__(256) void gemm_bt(const u16* __restrict__ A,
                                               const u16* __restrict__ Bt,
                                               OUT_T* __restrict__ C,
                                               int M, int N, int K) {
    __shared__ u16 As[128 * 64];
    __shared__ u16 Bs[128 * 64];
    const int tid = threadIdx.x;
    const int wave = tid >> 6, lane = tid & 63;
    const int lr = lane & 15, lq = lane >> 4;
    const int m0 = blockIdx.y * 128, n0 = blockIdx.x * 128;
    const int wr = (wave >> 1) * 64, wc = (wave & 1) * 64;

    floatx4 zf = {0.f, 0.f, 0.f, 0.f};
    floatx4 acc[4][4];
#pragma unroll
    for (int i = 0; i < 4; i++)
#pragma unroll
        for (int j = 0; j < 4; j++) acc[i][j] = zf;

    for (int k0 = 0; k0 < K; k0 += 64) {
        int4 ra[4], rb[4];
#pragma unroll
        for (int r = 0; r < 4; r++) {
            int idx = r * 256 + tid;
            int row = idx >> 3, c8 = (idx & 7) << 3;
            ra[r] = *(const int4*)(A + (size_t)(m0 + row) * K + k0 + c8);
            rb[r] = *(const int4*)(Bt + (size_t)(n0 + row) * K + k0 + c8);
        }
        __syncthreads();
#pragma unroll
        for (int r = 0; r < 4; r++) {
            int idx = r * 256 + tid;
            ((int4*)As)[idx] = ra[r];
            ((int4*)Bs)[idx] = rb[r];
        }
        __syncthreads();
#pragma unroll
        for (int kk = 0; kk < 64; kk += 32) {
            short8 af[4], bfr[4];
#pragma unroll
            for (int i = 0; i < 4; i++)
                af[i] = *(const short8*)(As + (wr + i * 16 + lr) * 64 + kk + lq * 8);
#pragma unroll
            for (int j = 0; j < 4; j++)
                bfr[j] = *(const short8*)(Bs + (wc + j * 16 + lr) * 64 + kk + lq * 8);
#pragma unroll
            for (int i = 0; i < 4; i++)
#pragma unroll
                for (int j = 0; j < 4; j++)
                    acc[i][j] = __builtin_amdgcn_mfma_f32_16x16x32_bf16(af[i], bfr[j], acc[i][j], 0, 0, 0);
        }
    }
#pragma unroll
    for (int i = 0; i < 4; i++)
#pragma unroll
        for (int j = 0; j < 4; j++)
#pragma unroll
            for (int r = 0; r < 4; r++) {
                int row = m0 + wr + i * 16 + lq * 4 + r;
                int col = n0 + wc + j * 16 + lr;
                if constexpr (sizeof(OUT_T) == 2)
                    C[(size_t)row * N + col] = f2bf(acc[i][j][r]);
                else
                    C[(size_t)row * N + col] = acc[i][j][r];
            }
}

// ==========================================================================
// RMS-norm + RoPE on Q (65536 rows) and K (32768 rows), in place (bf16).
// cos/sin/qw/kw are f32. One wave per 128-elem row; lane holds d=2l,2l+1.
// Q additionally scaled by D^-0.5 * log2(e) (exp2 softmax trick).
// ==========================================================================
__global__ __launch_bounds__(256) void norm_rope(u16* __restrict__ Q,
                                                 u16* __restrict__ Kk,
                                                 const float* __restrict__ cosb,
                                                 const float* __restrict__ sinb,
                                                 const float* __restrict__ qw,
                                                 const float* __restrict__ kw) {
    const int tid = threadIdx.x;
    const int wave = tid >> 6, lane = tid & 63;
    const int t = blockIdx.x * 4 + wave;  // 0..98303
    u16* ptr;
    const float* w;
    float scale;
    int bs;
    if (t < 65536) {
        bs = t >> 4;
        int h = t & 15;
        ptr = Q + (size_t)bs * 2048 + h * 128;
        w = qw;
        scale = 0.08838834764831845f * 1.4426950408889634f;  // D^-0.5 * log2(e)
    } else {
        int t2 = t - 65536;
        bs = t2 >> 3;
        int kvh = t2 & 7;
        ptr = Kk + (size_t)bs * 1024 + kvh * 128;
        w = kw;
        scale = 1.0f;
    }
    const int d = lane * 2;
    u32 xv = *(const u32*)(ptr + d);
    float x0 = bf2f((u16)(xv & 0xffff)), x1 = bf2f((u16)(xv >> 16));
    float ss = x0 * x0 + x1 * x1;
#pragma unroll
    for (int off = 1; off < 64; off <<= 1) ss += __shfl_xor(ss, off);
    float rn = rsqrtf(ss * (1.0f / 128.0f) + 1e-6f);
    float2 wv = *(const float2*)(w + d);
    float y0 = x0 * rn * wv.x;
    float y1 = x1 * rn * wv.y;
    float p0 = __shfl_xor(y0, 32);
    float p1 = __shfl_xor(y1, 32);
    float sgn = (lane < 32) ? -1.0f : 1.0f;
    float2 cv = *(const float2*)(cosb + (size_t)bs * 128 + d);
    float2 sv = *(const float2*)(sinb + (size_t)bs * 128 + d);
    float o0 = (y0 * cv.x + sgn * p0 * sv.x) * scale;
    float o1 = (y1 * cv.y + sgn * p1 * sv.y) * scale;
    *(u32*)(ptr + d) = (u32)f2bf(o0) | ((u32)f2bf(o1) << 16);
}

// ==========================================================================
// Causal GQA flash attention (all bf16 tensors).
// grid (S/128, NH, B). 256 threads = 4 waves x 32 q-rows.
// Q: (b,s,h,d) pre-scaled; K: (b,s,kv,d); Vt: (b,kv,d,s); O: (b,s,h,d)
// ==========================================================================
__global__ __launch_bounds__(256) void attn_kernel(const u16* __restrict__ Q,
                                                   const u16* __restrict__ Kg,
                                                   const u16* __restrict__ Vt,
                                                   u16* __restrict__ O) {
    __shared__ u16 Qs[128 * 128];
    __shared__ u16 Ks[128 * 128];
    __shared__ u16 Vs[128 * 128];
    __shared__ u16 Ps[128 * 128];
    const int tid = threadIdx.x;
    const int wave = tid >> 6, lane = tid & 63;
    const int lr = lane & 15, lq = lane >> 4;
    const int qt = blockIdx.x, h = blockIdx.y, b = blockIdx.z;
    const int kv = h >> 1;
    const int q0 = qt * 128;
    const int wq = wave * 32;

    // stage Q tile once (128 rows x 128 d)
#pragma unroll
    for (int r = 0; r < 8; r++) {
        int idx = r * 256 + tid;
        int row = idx >> 4, c8 = (idx & 15) << 3;
        ((int4*)Qs)[idx] = *(const int4*)(Q + (size_t)(b * 2048 + q0 + row) * 2048 + h * 128 + c8);
    }

    floatx4 zf = {0.f, 0.f, 0.f, 0.f};
    floatx4 oacc[2][8];
#pragma unroll
    for (int i = 0; i < 2; i++)
#pragma unroll
        for (int j = 0; j < 8; j++) oacc[i][j] = zf;
    float mstate[2][4], lstate[2][4];
#pragma unroll
    for (int i = 0; i < 2; i++)
#pragma unroll
        for (int r = 0; r < 4; r++) {
            mstate[i][r] = -1e30f;
            lstate[i][r] = 0.f;
        }

    for (int kt = 0; kt <= qt; kt++) {
        const int k0 = kt * 128;
        __syncthreads();  // previous iter consumers done (also covers Q staging)
#pragma unroll
        for (int r = 0; r < 8; r++) {
            int idx = r * 256 + tid;
            int row = idx >> 4, c8 = (idx & 15) << 3;
            ((int4*)Ks)[idx] = *(const int4*)(Kg + (size_t)(b * 2048 + k0 + row) * 1024 + kv * 128 + c8);
            ((int4*)Vs)[idx] = *(const int4*)(Vt + (size_t)((b * 8 + kv) * 128 + row) * 2048 + k0 + c8);
        }
        __syncthreads();

        // S = Q K^T  (wave: 32 q-rows x 128 keys)
        floatx4 sacc[2][8];
#pragma unroll
        for (int i = 0; i < 2; i++)
#pragma unroll
            for (int j = 0; j < 8; j++) sacc[i][j] = zf;
#pragma unroll
        for (int kk = 0; kk < 128; kk += 32) {
            short8 af[2], bfr[8];
#pragma unroll
            for (int i = 0; i < 2; i++)
                af[i] = *(const short8*)(Qs + (wq + i * 16 + lr) * 128 + kk + lq * 8);
#pragma unroll
            for (int j = 0; j < 8; j++)
                bfr[j] = *(const short8*)(Ks + (j * 16 + lr) * 128 + kk + lq * 8);
#pragma unroll
            for (int i = 0; i < 2; i++)
#pragma unroll
                for (int j = 0; j < 8; j++)
                    sacc[i][j] = __builtin_amdgcn_mfma_f32_16x16x32_bf16(af[i], bfr[j], sacc[i][j], 0, 0, 0);
        }

        // causal mask on diagonal tile
        if (kt == qt) {
#pragma unroll
            for (int i = 0; i < 2; i++)
#pragma unroll
                for (int j = 0; j < 8; j++) {
                    int kmq = j * 16 + lr - (wq + i * 16 + lq * 4);
#pragma unroll
                    for (int r = 0; r < 4; r++)
                        if (kmq > r) sacc[i][j][r] = -1e30f;
                }
        }

        // online softmax (rows live in 16-lane groups; reduce via shfl_xor<16)
        float alpha[2][4];
#pragma unroll
        for (int i = 0; i < 2; i++)
#pragma unroll
            for (int r = 0; r < 4; r++) {
                float mx = sacc[i][0][r];
#pragma unroll
                for (int j = 1; j < 8; j++) mx = fmaxf(mx, sacc[i][j][r]);
#pragma unroll
                for (int off = 1; off < 16; off <<= 1) mx = fmaxf(mx, __shfl_xor(mx, off));
                float mnew = fmaxf(mstate[i][r], mx);
                float a = exp2f(mstate[i][r] - mnew);
                mstate[i][r] = mnew;
                float rs = 0.f;
#pragma unroll
                for (int j = 0; j < 8; j++) {
                    float p = exp2f(sacc[i][j][r] - mnew);
                    sacc[i][j][r] = p;
                    rs += p;
                }
#pragma unroll
                for (int off = 1; off < 16; off <<= 1) rs += __shfl_xor(rs, off);
                lstate[i][r] = lstate[i][r] * a + rs;
                alpha[i][r] = a;
            }

        // write P (bf16) to LDS, rescale O
#pragma unroll
        for (int i = 0; i < 2; i++)
#pragma unroll
            for (int j = 0; j < 8; j++)
#pragma unroll
                for (int r = 0; r < 4; r++)
                    Ps[(wq + i * 16 + lq * 4 + r) * 128 + j * 16 + lr] = f2bf(sacc[i][j][r]);
#pragma unroll
        for (int i = 0; i < 2; i++)
#pragma unroll
            for (int j = 0; j < 8; j++)
#pragma unroll
                for (int r = 0; r < 4; r++) oacc[i][j][r] *= alpha[i][r];
        __syncthreads();  // P visibility (uniform control flow)

        // O += P @ V   (B-operand from Vs: n=d, k=key contiguous)
#pragma unroll
        for (int kk = 0; kk < 128; kk += 32) {
            short8 af[2], bfr[8];
#pragma unroll
            for (int i = 0; i < 2; i++)
                af[i] = *(const short8*)(Ps + (wq + i * 16 + lr) * 128 + kk + lq * 8);
#pragma unroll
            for (int j = 0; j < 8; j++)
                bfr[j] = *(const short8*)(Vs + (j * 16 + lr) * 128 + kk + lq * 8);
#pragma unroll
            for (int i = 0; i < 2; i++)
#pragma unroll
                for (int j = 0; j < 8; j++)
                    oacc[i][j] = __builtin_amdgcn_mfma_f32_16x16x32_bf16(af[i], bfr[j], oacc[i][j], 0, 0, 0);
        }
    }

    // epilogue: O / l
#pragma unroll
    for (int i = 0; i < 2; i++)
#pragma unroll
        for (int j = 0; j < 8; j++)
#pragma unroll
            for (int r = 0; r < 4; r++) {
                int row = q0 + wq + i * 16 + lq * 4 + r;
                float v = oacc[i][j][r] / lstate[i][r];
                O[(size_t)(b * 2048 + row) * 2048 + h * 128 + j * 16 + lr] = f2bf(v);
            }
}

// ==========================================================================
extern "C" void kernel_launch(void* const* d_in, const int* in_sizes, int n_in,
                              void* d_out, int out_size, void* d_ws, size_t ws_size,
                              hipStream_t stream) {
    const float* X = (const float*)d_in[0];
    const float* cosb = (const float*)d_in[1];
    const float* sinb = (const float*)d_in[2];
    const float* Wq = (const float*)d_in[3];
    const float* Wk = (const float*)d_in[4];
    const float* Wv = (const float*)d_in[5];
    const float* Wo = (const float*)d_in[6];
    const float* qw = (const float*)d_in[7];
    const float* kw = (const float*)d_in[8];
    float* out = (float*)d_out;
    u16* ws = (u16*)d_ws;

    u16* WqT = ws;                  // 2048x2048 -> 4194304
    u16* WkT = WqT + 4194304;       // 1024x2048 -> 2097152
    u16* WvT = WkT + 2097152;       // 2097152
    u16* WoT = WvT + 2097152;       // 4194304
    u16* Xb = WoT + 4194304;        // 4096x2048 -> 8388608
    u16* Qb = Xb + 8388608;         // 8388608
    u16* Kb = Qb + 8388608;         // 4194304
    u16* Vb = Kb + 4194304;         // 4194304
    u16* Vtb = Vb + 4194304;        // 4194304
    u16* Ob = WqT;                  // alias: WqT/WkT/WvT dead after QKV GEMMs
    // total 41,943,040 u16 = 83.9 MB

    dim3 tb(32, 32);
    transpose_wc<<<dim3(64, 64), tb, 0, stream>>>(Wq, WqT, 2048, 2048);
    transpose_wc<<<dim3(32, 64), tb, 0, stream>>>(Wk, WkT, 2048, 1024);
    transpose_wc<<<dim3(32, 64), tb, 0, stream>>>(Wv, WvT, 2048, 1024);
    transpose_wc<<<dim3(64, 64), tb, 0, stream>>>(Wo, WoT, 2048, 2048);
    convert_x<<<8192, 256, 0, stream>>>(X, Xb, 2097152);

    gemm_bt<u16><<<dim3(16, 32), 256, 0, stream>>>(Xb, WqT, Qb, 4096, 2048, 2048);
    gemm_bt<u16><<<dim3(8, 32), 256, 0, stream>>>(Xb, WkT, Kb, 4096, 1024, 2048);
    gemm_bt<u16><<<dim3(8, 32), 256, 0, stream>>>(Xb, WvT, Vb, 4096, 1024, 2048);

    norm_rope<<<24576, 256, 0, stream>>>(Qb, Kb, cosb, sinb, qw, kw);
    transpose_v<<<dim3(64, 4, 16), tb, 0, stream>>>(Vb, Vtb);

    attn_kernel<<<dim3(16, 16, 2), 256, 0, stream>>>(Qb, Kb, Vtb, Ob);

    gemm_bt<float><<<dim3(16, 32), 256, 0, stream>>>(Ob, WoT, out, 4096, 2048, 2048);
}

// Round 4
// 485.244 us; speedup vs baseline: 2.0361x; 2.0361x over previous
//
#include <hip/hip_runtime.h>

typedef unsigned short u16;
typedef unsigned int u32;
typedef unsigned long long u64;
typedef __attribute__((ext_vector_type(8))) short short8;
typedef __attribute__((ext_vector_type(4))) float floatx4;

// ---- bf16 <-> f32 helpers (raw bits, RNE) ----
__device__ __forceinline__ float bf2f(u16 u) {
    u32 x = ((u32)u) << 16;
    float f;
    __builtin_memcpy(&f, &x, 4);
    return f;
}
__device__ __forceinline__ u16 f2bf(float f) {
    u32 x;
    __builtin_memcpy(&x, &f, 4);
    u32 r = (x + 0x7fffu + ((x >> 16) & 1u)) >> 16;
    return (u16)r;
}

// ==========================================================================
// Convert f32 -> bf16, 4 elems/thread
// ==========================================================================
__global__ __launch_bounds__(256) void convert_x(const float* __restrict__ in,
                                                 u16* __restrict__ out) {
    int i = blockIdx.x * 256 + threadIdx.x;
    float4 v = *(const float4*)(in + (size_t)i * 4);
    u16 o[4] = {f2bf(v.x), f2bf(v.y), f2bf(v.z), f2bf(v.w)};
    *(u64*)(out + (size_t)i * 4) = *(u64*)o;
}

// ==========================================================================
// Convert + transpose: in f32 (R x C) -> out bf16 (C x R)
// ==========================================================================
__global__ __launch_bounds__(1024) void transpose_wc(const float* __restrict__ in,
                                                     u16* __restrict__ out,
                                                     int R, int C) {
    __shared__ u16 t[32][33];
    const int tx = threadIdx.x, ty = threadIdx.y;
    const int c0 = blockIdx.x * 32, r0 = blockIdx.y * 32;
    t[ty][tx] = f2bf(in[(size_t)(r0 + ty) * C + c0 + tx]);
    __syncthreads();
    out[(size_t)(c0 + ty) * R + r0 + tx] = t[tx][ty];
}

// V inside QKV (b,s,4096 row: [Q2048|K1024|V1024]) -> Vt (b,kv,d,s)
__global__ __launch_bounds__(1024) void transpose_v(const u16* __restrict__ QKV,
                                                    u16* __restrict__ Vt) {
    __shared__ u16 t[32][33];
    const int tx = threadIdx.x, ty = threadIdx.y;
    const int b = blockIdx.z >> 3, kv = blockIdx.z & 7;
    const int s0 = blockIdx.x * 32, d0 = blockIdx.y * 32;
    t[ty][tx] = QKV[(size_t)(b * 2048 + s0 + ty) * 4096 + 3072 + kv * 128 + d0 + tx];
    __syncthreads();
    Vt[(size_t)((b * 8 + kv) * 128 + d0 + ty) * 2048 + s0 + tx] = t[tx][ty];
}

// ==========================================================================
// GEMM: C[M,N] = A[M,K] @ Bt[N,K]^T (bf16 in, fp32 acc, OUT_T out)
// tile 128x128, BK=64, 256 threads; global_load_lds width-16 staging (m97)
// ==========================================================================
template <typename OUT_T>
__global__ __launch_bounds__(256) void gemm_bt(const u16* __restrict__ A,
                                               const u16* __restrict__ Bt,
                                               OUT_T* __restrict__ C,
                                               int M, int N, int K) {
    __shared__ __align__(16) u16 As[128 * 64];
    __shared__ __align__(16) u16 Bs[128 * 64];
    const int tid = threadIdx.x;
    const int wave = tid >> 6, lane = tid & 63;
    const int lr = lane & 15, lq = lane >> 4;
    const int m0 = blockIdx.y * 128, n0 = blockIdx.x * 128;
    const int wr = (wave >> 1) * 64, wc = (wave & 1) * 64;

    floatx4 zf = {0.f, 0.f, 0.f, 0.f};
    floatx4 acc[4][4];
#pragma unroll
    for (int i = 0; i < 4; i++)
#pragma unroll
        for (int j = 0; j < 4; j++) acc[i][j] = zf;

    const int lrow = lane >> 3;          // 0..7 within chunk
    const int lcol = (lane & 7) << 3;    // 0..56

    for (int k0 = 0; k0 < K; k0 += 64) {
        __syncthreads();  // protect As/Bs from overwrite while previous iter reads
#pragma unroll
        for (int c = 0; c < 4; c++) {
            int chunk = (wave << 2) + c;          // 0..15
            int row = (chunk << 3) + lrow;        // 0..127
            __builtin_amdgcn_global_load_lds(
                (const __attribute__((address_space(1))) void*)(A + (size_t)(m0 + row) * K + k0 + lcol),
                (__attribute__((address_space(3))) void*)(As + (chunk << 9)), 16, 0, 0);
            __builtin_amdgcn_global_load_lds(
                (const __attribute__((address_space(1))) void*)(Bt + (size_t)(n0 + row) * K + k0 + lcol),
                (__attribute__((address_space(3))) void*)(Bs + (chunk << 9)), 16, 0, 0);
        }
        __syncthreads();  // vmcnt(0) drain makes staged data visible
#pragma unroll
        for (int kk = 0; kk < 64; kk += 32) {
            short8 af[4], bfr[4];
#pragma unroll
            for (int i = 0; i < 4; i++)
                af[i] = *(const short8*)(As + (wr + i * 16 + lr) * 64 + kk + lq * 8);
#pragma unroll
            for (int j = 0; j < 4; j++)
                bfr[j] = *(const short8*)(Bs + (wc + j * 16 + lr) * 64 + kk + lq * 8);
#pragma unroll
            for (int i = 0; i < 4; i++)
#pragma unroll
                for (int j = 0; j < 4; j++)
                    acc[i][j] = __builtin_amdgcn_mfma_f32_16x16x32_bf16(af[i], bfr[j], acc[i][j], 0, 0, 0);
        }
    }
#pragma unroll
    for (int i = 0; i < 4; i++)
#pragma unroll
        for (int j = 0; j < 4; j++)
#pragma unroll
            for (int r = 0; r < 4; r++) {
                int row = m0 + wr + i * 16 + lq * 4 + r;
                int col = n0 + wc + j * 16 + lr;
                if constexpr (sizeof(OUT_T) == 2)
                    C[(size_t)row * N + col] = f2bf(acc[i][j][r]);
                else
                    C[(size_t)row * N + col] = acc[i][j][r];
            }
}

// ==========================================================================
// RMS-norm + RoPE on Q/K inside QKV (row stride 4096), in place (bf16).
// One wave per 128-elem head row. Q also scaled by D^-0.5 * log2(e).
// ==========================================================================
__global__ __launch_bounds__(256) void norm_rope(u16* __restrict__ QKV,
                                                 const float* __restrict__ cosb,
                                                 const float* __restrict__ sinb,
                                                 const float* __restrict__ qw,
                                                 const float* __restrict__ kw) {
    const int tid = threadIdx.x;
    const int wave = tid >> 6, lane = tid & 63;
    const int t = blockIdx.x * 4 + wave;  // 0..98303
    u16* ptr;
    const float* w;
    float scale;
    int bs;
    if (t < 65536) {
        bs = t >> 4;
        ptr = QKV + (size_t)bs * 4096 + (t & 15) * 128;
        w = qw;
        scale = 0.08838834764831845f * 1.4426950408889634f;  // D^-0.5 * log2(e)
    } else {
        int t2 = t - 65536;
        bs = t2 >> 3;
        ptr = QKV + (size_t)bs * 4096 + 2048 + (t2 & 7) * 128;
        w = kw;
        scale = 1.0f;
    }
    const int d = lane * 2;
    u32 xv = *(const u32*)(ptr + d);
    float x0 = bf2f((u16)(xv & 0xffff)), x1 = bf2f((u16)(xv >> 16));
    float ss = x0 * x0 + x1 * x1;
#pragma unroll
    for (int off = 1; off < 64; off <<= 1) ss += __shfl_xor(ss, off);
    float rn = rsqrtf(ss * (1.0f / 128.0f) + 1e-6f);
    float2 wv = *(const float2*)(w + d);
    float y0 = x0 * rn * wv.x;
    float y1 = x1 * rn * wv.y;
    float p0 = __shfl_xor(y0, 32);
    float p1 = __shfl_xor(y1, 32);
    float sgn = (lane < 32) ? -1.0f : 1.0f;
    float2 cv = *(const float2*)(cosb + (size_t)bs * 128 + d);
    float2 sv = *(const float2*)(sinb + (size_t)bs * 128 + d);
    float o0 = (y0 * cv.x + sgn * p0 * sv.x) * scale;
    float o1 = (y1 * cv.y + sgn * p1 * sv.y) * scale;
    *(u32*)(ptr + d) = (u32)f2bf(o0) | ((u32)f2bf(o1) << 16);
}

// ==========================================================================
// Causal GQA flash attention, transposed-score formulation.
// grid (S/128, NH, B), 256 thr = 4 waves x 32 q-rows; key tile 64.
// S^T = K@Q^T so softmax rows sit on lane&15; P^T written as 8B packs;
// PV reads P and V as b128. Q frags live in registers.
// QKV row stride 4096 (Q at 0, K at 2048); Vt (b,kv,d,s); O (b,s,h,d).
// ==========================================================================
__global__ __launch_bounds__(256, 3) void attn_kernel(const u16* __restrict__ QKV,
                                                      const u16* __restrict__ Vt,
                                                      u16* __restrict__ O) {
    __shared__ __align__(16) u16 Ks[64 * 136];   // [key][d]  pad 136
    __shared__ __align__(16) u16 Vs[128 * 72];   // [d][key]  pad 72
    __shared__ __align__(16) u16 Ps[128 * 72];   // [qrow][key] pad 72
    const int tid = threadIdx.x;
    const int wave = tid >> 6, lane = tid & 63;
    const int lr = lane & 15, lq = lane >> 4;
    const int qt = 15 - blockIdx.x;  // heavy tiles dispatch first
    const int h = blockIdx.y, b = blockIdx.z;
    const int kv = h >> 1;
    const int q0 = qt * 128;
    const int wq = wave * 32;

    // Q fragments in registers (B-operand layout: n=qrow on lr, k=d on lq*8+j)
    short8 qf[2][4];
#pragma unroll
    for (int i = 0; i < 2; i++)
#pragma unroll
        for (int t = 0; t < 4; t++)
            qf[i][t] = *(const short8*)(QKV + (size_t)(b * 2048 + q0 + wq + i * 16 + lr) * 4096 + h * 128 + t * 32 + lq * 8);

    floatx4 zf = {0.f, 0.f, 0.f, 0.f};
    floatx4 oacc[2][8];
#pragma unroll
    for (int im = 0; im < 2; im++)
#pragma unroll
        for (int jn = 0; jn < 8; jn++) oacc[im][jn] = zf;
    float mstate[2] = {-1e30f, -1e30f};
    float lstate[2] = {0.f, 0.f};

    const int nIter = (qt + 1) * 2;
    for (int kt = 0; kt < nIter; kt++) {
        const int k0 = kt * 64;
        __syncthreads();  // prev iter done reading Ks/Vs
        {
            // Ks: 64 keys x 128 d  -> 1024 int4;  Vs: 128 d x 64 keys -> 1024 int4
            int4 rk[4], rv[4];
#pragma unroll
            for (int r = 0; r < 4; r++) {
                int idx = r * 256 + tid;  // 0..1023
                rk[r] = *(const int4*)(QKV + (size_t)(b * 2048 + k0 + (idx >> 4)) * 4096 + 2048 + kv * 128 + ((idx & 15) << 3));
                rv[r] = *(const int4*)(Vt + (size_t)((b * 8 + kv) * 128 + (idx >> 3)) * 2048 + k0 + ((idx & 7) << 3));
            }
#pragma unroll
            for (int r = 0; r < 4; r++) {
                int idx = r * 256 + tid;
                *(int4*)(Ks + (idx >> 4) * 136 + ((idx & 15) << 3)) = rk[r];
                *(int4*)(Vs + (idx >> 3) * 72 + ((idx & 7) << 3)) = rv[r];
            }
        }
        __syncthreads();

        // S^T = K @ Q^T : sacc[jm][i]; key = jm*16+lq*4+r, qrow = i*16+lr
        floatx4 sacc[4][2];
#pragma unroll
        for (int jm = 0; jm < 4; jm++)
#pragma unroll
            for (int i = 0; i < 2; i++) sacc[jm][i] = zf;
#pragma unroll
        for (int t = 0; t < 4; t++) {
            short8 a[4];
#pragma unroll
            for (int jm = 0; jm < 4; jm++)
                a[jm] = *(const short8*)(Ks + (jm * 16 + lr) * 136 + t * 32 + lq * 8);
#pragma unroll
            for (int jm = 0; jm < 4; jm++)
#pragma unroll
                for (int i = 0; i < 2; i++)
                    sacc[jm][i] = __builtin_amdgcn_mfma_f32_16x16x32_bf16(a[jm], qf[i][t], sacc[jm][i], 0, 0, 0);
        }

        // causal mask: key_g > qrow_g  (wave-uniform branch)
        if (k0 + 63 > q0 + wq) {
#pragma unroll
            for (int jm = 0; jm < 4; jm++)
#pragma unroll
                for (int i = 0; i < 2; i++) {
                    int diff = (q0 + wq + i * 16 + lr) - (k0 + jm * 16 + lq * 4);
#pragma unroll
                    for (int r = 0; r < 4; r++)
                        if (r > diff) sacc[jm][i][r] = -1e30f;
                }
        }

        // online softmax per qrow (qrow on lane&15; reduce across quads only)
        float alpha[2];
#pragma unroll
        for (int i = 0; i < 2; i++) {
            float mx = -1e30f;
#pragma unroll
            for (int jm = 0; jm < 4; jm++)
#pragma unroll
                for (int r = 0; r < 4; r++) mx = fmaxf(mx, sacc[jm][i][r]);
            mx = fmaxf(mx, __shfl_xor(mx, 16));
            mx = fmaxf(mx, __shfl_xor(mx, 32));
            float mnew = fmaxf(mstate[i], mx);
            float a = exp2f(mstate[i] - mnew);
            mstate[i] = mnew;
            float rs = 0.f;
#pragma unroll
            for (int jm = 0; jm < 4; jm++)
#pragma unroll
                for (int r = 0; r < 4; r++) {
                    float p = exp2f(sacc[jm][i][r] - mnew);
                    sacc[jm][i][r] = p;
                    rs += p;
                }
            rs += __shfl_xor(rs, 16);
            rs += __shfl_xor(rs, 32);
            lstate[i] = lstate[i] * a + rs;
            alpha[i] = a;
        }

        // P^T -> Ps[qrow][key]: lane packs 4 consecutive keys = 8B write
#pragma unroll
        for (int i = 0; i < 2; i++)
#pragma unroll
            for (int jm = 0; jm < 4; jm++) {
                u16 o[4] = {f2bf(sacc[jm][i][0]), f2bf(sacc[jm][i][1]),
                            f2bf(sacc[jm][i][2]), f2bf(sacc[jm][i][3])};
                *(u64*)(Ps + (wq + i * 16 + lr) * 72 + jm * 16 + lq * 4) = *(u64*)o;
            }

        // rescale O: alpha lives at qrow=lr; oacc has qrow=im*16+lq*4+r
        float ao[2][4];
#pragma unroll
        for (int im = 0; im < 2; im++)
#pragma unroll
            for (int r = 0; r < 4; r++) ao[im][r] = __shfl(alpha[im], lq * 4 + r);
#pragma unroll
        for (int im = 0; im < 2; im++)
#pragma unroll
            for (int jn = 0; jn < 8; jn++)
#pragma unroll
                for (int r = 0; r < 4; r++) oacc[im][jn][r] *= ao[im][r];

        // O += P @ V (A=P from Ps, B=V from Vs; both b128)
#pragma unroll
        for (int t = 0; t < 2; t++) {
            short8 pa[2], vb[8];
#pragma unroll
            for (int im = 0; im < 2; im++)
                pa[im] = *(const short8*)(Ps + (wq + im * 16 + lr) * 72 + t * 32 + lq * 8);
#pragma unroll
            for (int jn = 0; jn < 8; jn++)
                vb[jn] = *(const short8*)(Vs + (jn * 16 + lr) * 72 + t * 32 + lq * 8);
#pragma unroll
            for (int im = 0; im < 2; im++)
#pragma unroll
                for (int jn = 0; jn < 8; jn++)
                    oacc[im][jn] = __builtin_amdgcn_mfma_f32_16x16x32_bf16(pa[im], vb[jn], oacc[im][jn], 0, 0, 0);
        }
    }

    // epilogue: O / l   (l at qrow=lr -> transpose to qrow=lq*4+r)
    float lo[2][4];
#pragma unroll
    for (int im = 0; im < 2; im++)
#pragma unroll
        for (int r = 0; r < 4; r++) lo[im][r] = __shfl(lstate[im], lq * 4 + r);
#pragma unroll
    for (int im = 0; im < 2; im++)
#pragma unroll
        for (int jn = 0; jn < 8; jn++)
#pragma unroll
            for (int r = 0; r < 4; r++) {
                int row = q0 + wq + im * 16 + lq * 4 + r;
                O[(size_t)(b * 2048 + row) * 2048 + h * 128 + jn * 16 + lr] =
                    f2bf(oacc[im][jn][r] / lo[im][r]);
            }
}

// ==========================================================================
extern "C" void kernel_launch(void* const* d_in, const int* in_sizes, int n_in,
                              void* d_out, int out_size, void* d_ws, size_t ws_size,
                              hipStream_t stream) {
    const float* X = (const float*)d_in[0];
    const float* cosb = (const float*)d_in[1];
    const float* sinb = (const float*)d_in[2];
    const float* Wq = (const float*)d_in[3];
    const float* Wk = (const float*)d_in[4];
    const float* Wv = (const float*)d_in[5];
    const float* Wo = (const float*)d_in[6];
    const float* qw = (const float*)d_in[7];
    const float* kw = (const float*)d_in[8];
    float* out = (float*)d_out;
    u16* ws = (u16*)d_ws;

    u16* WqkvT = ws;                    // 4096x2048 = 8388608
    u16* WoT = WqkvT + 8388608;         // 4194304
    u16* Xb = WoT + 4194304;            // 8388608 (dead after QKV GEMM)
    u16* QKVb = Xb + 8388608;           // 4096x4096 = 16777216
    u16* Vtb = QKVb + 16777216;         // 4194304
    u16* Ob = Xb;                       // alias
    // total 41,943,040 u16 = 83.9 MB

    dim3 tb(32, 32);
    transpose_wc<<<dim3(64, 64), tb, 0, stream>>>(Wq, WqkvT, 2048, 2048);
    transpose_wc<<<dim3(32, 64), tb, 0, stream>>>(Wk, WqkvT + 2048 * 2048, 2048, 1024);
    transpose_wc<<<dim3(32, 64), tb, 0, stream>>>(Wv, WqkvT + 3072 * 2048, 2048, 1024);
    transpose_wc<<<dim3(64, 64), tb, 0, stream>>>(Wo, WoT, 2048, 2048);
    convert_x<<<8192, 256, 0, stream>>>(X, Xb);

    gemm_bt<u16><<<dim3(32, 32), 256, 0, stream>>>(Xb, WqkvT, QKVb, 4096, 4096, 2048);

    norm_rope<<<24576, 256, 0, stream>>>(QKVb, cosb, sinb, qw, kw);
    transpose_v<<<dim3(64, 4, 16), tb, 0, stream>>>(QKVb, Vtb);

    attn_kernel<<<dim3(16, 16, 2), 256, 0, stream>>>(QKVb, Vtb, Ob);

    gemm_bt<float><<<dim3(16, 32), 256, 0, stream>>>(Ob, WoT, out, 4096, 2048, 2048);
}

// Round 5
// 449.673 us; speedup vs baseline: 2.1972x; 1.0791x over previous
//
#include <hip/hip_runtime.h>

typedef unsigned short u16;
typedef unsigned int u32;
typedef unsigned long long u64;
typedef __attribute__((ext_vector_type(8))) short short8;
typedef __attribute__((ext_vector_type(4))) float floatx4;

// ---- bf16 <-> f32 helpers (raw bits, RNE) ----
__device__ __forceinline__ float bf2f(u16 u) {
    u32 x = ((u32)u) << 16;
    float f;
    __builtin_memcpy(&f, &x, 4);
    return f;
}
__device__ __forceinline__ u16 f2bf(float f) {
    u32 x;
    __builtin_memcpy(&x, &f, 4);
    u32 r = (x + 0x7fffu + ((x >> 16) & 1u)) >> 16;
    return (u16)r;
}

// ==========================================================================
// Convert f32 -> bf16, 4 elems/thread
// ==========================================================================
__global__ __launch_bounds__(256) void convert_x(const float* __restrict__ in,
                                                 u16* __restrict__ out) {
    int i = blockIdx.x * 256 + threadIdx.x;
    float4 v = *(const float4*)(in + (size_t)i * 4);
    u16 o[4] = {f2bf(v.x), f2bf(v.y), f2bf(v.z), f2bf(v.w)};
    *(u64*)(out + (size_t)i * 4) = *(u64*)o;
}

// ==========================================================================
// Convert + transpose: in f32 (R x C) -> out bf16 (C x R)
// ==========================================================================
__global__ __launch_bounds__(1024) void transpose_wc(const float* __restrict__ in,
                                                     u16* __restrict__ out,
                                                     int R, int C) {
    __shared__ u16 t[32][33];
    const int tx = threadIdx.x, ty = threadIdx.y;
    const int c0 = blockIdx.x * 32, r0 = blockIdx.y * 32;
    t[ty][tx] = f2bf(in[(size_t)(r0 + ty) * C + c0 + tx]);
    __syncthreads();
    out[(size_t)(c0 + ty) * R + r0 + tx] = t[tx][ty];
}

// V inside QKV (b,s,4096 row: [Q2048|K1024|V1024]) -> Vt (b,kv,d,s)
__global__ __launch_bounds__(1024) void transpose_v(const u16* __restrict__ QKV,
                                                    u16* __restrict__ Vt) {
    __shared__ u16 t[32][33];
    const int tx = threadIdx.x, ty = threadIdx.y;
    const int b = blockIdx.z >> 3, kv = blockIdx.z & 7;
    const int s0 = blockIdx.x * 32, d0 = blockIdx.y * 32;
    t[ty][tx] = QKV[(size_t)(b * 2048 + s0 + ty) * 4096 + 3072 + kv * 128 + d0 + tx];
    __syncthreads();
    Vt[(size_t)((b * 8 + kv) * 128 + d0 + ty) * 2048 + s0 + tx] = t[tx][ty];
}

// ==========================================================================
// GEMM: C[M,N] = A[M,K] @ Bt[N,K]^T (bf16 in, fp32 acc, OUT_T out)
// tile 128x128, BK=64, 256 threads; global_load_lds width-16 staging (m97)
// ==========================================================================
template <typename OUT_T>
__global__ __launch_bounds__(256) void gemm_bt(const u16* __restrict__ A,
                                               const u16* __restrict__ Bt,
                                               OUT_T* __restrict__ C,
                                               int M, int N, int K) {
    __shared__ __align__(16) u16 As[128 * 64];
    __shared__ __align__(16) u16 Bs[128 * 64];
    const int tid = threadIdx.x;
    const int wave = tid >> 6, lane = tid & 63;
    const int lr = lane & 15, lq = lane >> 4;
    const int m0 = blockIdx.y * 128, n0 = blockIdx.x * 128;
    const int wr = (wave >> 1) * 64, wc = (wave & 1) * 64;

    floatx4 zf = {0.f, 0.f, 0.f, 0.f};
    floatx4 acc[4][4];
#pragma unroll
    for (int i = 0; i < 4; i++)
#pragma unroll
        for (int j = 0; j < 4; j++) acc[i][j] = zf;

    const int lrow = lane >> 3;          // 0..7 within chunk
    const int lcol = (lane & 7) << 3;    // 0..56

    for (int k0 = 0; k0 < K; k0 += 64) {
        __syncthreads();  // protect As/Bs from overwrite while previous iter reads
#pragma unroll
        for (int c = 0; c < 4; c++) {
            int chunk = (wave << 2) + c;          // 0..15
            int row = (chunk << 3) + lrow;        // 0..127
            __builtin_amdgcn_global_load_lds(
                (const __attribute__((address_space(1))) void*)(A + (size_t)(m0 + row) * K + k0 + lcol),
                (__attribute__((address_space(3))) void*)(As + (chunk << 9)), 16, 0, 0);
            __builtin_amdgcn_global_load_lds(
                (const __attribute__((address_space(1))) void*)(Bt + (size_t)(n0 + row) * K + k0 + lcol),
                (__attribute__((address_space(3))) void*)(Bs + (chunk << 9)), 16, 0, 0);
        }
        __syncthreads();  // vmcnt(0) drain makes staged data visible
#pragma unroll
        for (int kk = 0; kk < 64; kk += 32) {
            short8 af[4], bfr[4];
#pragma unroll
            for (int i = 0; i < 4; i++)
                af[i] = *(const short8*)(As + (wr + i * 16 + lr) * 64 + kk + lq * 8);
#pragma unroll
            for (int j = 0; j < 4; j++)
                bfr[j] = *(const short8*)(Bs + (wc + j * 16 + lr) * 64 + kk + lq * 8);
#pragma unroll
            for (int i = 0; i < 4; i++)
#pragma unroll
                for (int j = 0; j < 4; j++)
                    acc[i][j] = __builtin_amdgcn_mfma_f32_16x16x32_bf16(af[i], bfr[j], acc[i][j], 0, 0, 0);
        }
    }
#pragma unroll
    for (int i = 0; i < 4; i++)
#pragma unroll
        for (int j = 0; j < 4; j++)
#pragma unroll
            for (int r = 0; r < 4; r++) {
                int row = m0 + wr + i * 16 + lq * 4 + r;
                int col = n0 + wc + j * 16 + lr;
                if constexpr (sizeof(OUT_T) == 2)
                    C[(size_t)row * N + col] = f2bf(acc[i][j][r]);
                else
                    C[(size_t)row * N + col] = acc[i][j][r];
            }
}

// ==========================================================================
// RMS-norm + RoPE on Q/K inside QKV (row stride 4096), in place (bf16).
// One wave per 128-elem head row. Q also scaled by D^-0.5 * log2(e).
// ==========================================================================
__global__ __launch_bounds__(256) void norm_rope(u16* __restrict__ QKV,
                                                 const float* __restrict__ cosb,
                                                 const float* __restrict__ sinb,
                                                 const float* __restrict__ qw,
                                                 const float* __restrict__ kw) {
    const int tid = threadIdx.x;
    const int wave = tid >> 6, lane = tid & 63;
    const int t = blockIdx.x * 4 + wave;  // 0..98303
    u16* ptr;
    const float* w;
    float scale;
    int bs;
    if (t < 65536) {
        bs = t >> 4;
        ptr = QKV + (size_t)bs * 4096 + (t & 15) * 128;
        w = qw;
        scale = 0.08838834764831845f * 1.4426950408889634f;  // D^-0.5 * log2(e)
    } else {
        int t2 = t - 65536;
        bs = t2 >> 3;
        ptr = QKV + (size_t)bs * 4096 + 2048 + (t2 & 7) * 128;
        w = kw;
        scale = 1.0f;
    }
    const int d = lane * 2;
    u32 xv = *(const u32*)(ptr + d);
    float x0 = bf2f((u16)(xv & 0xffff)), x1 = bf2f((u16)(xv >> 16));
    float ss = x0 * x0 + x1 * x1;
#pragma unroll
    for (int off = 1; off < 64; off <<= 1) ss += __shfl_xor(ss, off);
    float rn = rsqrtf(ss * (1.0f / 128.0f) + 1e-6f);
    float2 wv = *(const float2*)(w + d);
    float y0 = x0 * rn * wv.x;
    float y1 = x1 * rn * wv.y;
    float p0 = __shfl_xor(y0, 32);
    float p1 = __shfl_xor(y1, 32);
    float sgn = (lane < 32) ? -1.0f : 1.0f;
    float2 cv = *(const float2*)(cosb + (size_t)bs * 128 + d);
    float2 sv = *(const float2*)(sinb + (size_t)bs * 128 + d);
    float o0 = (y0 * cv.x + sgn * p0 * sv.x) * scale;
    float o1 = (y1 * cv.y + sgn * p1 * sv.y) * scale;
    *(u32*)(ptr + d) = (u32)f2bf(o0) | ((u32)f2bf(o1) << 16);
}

// ==========================================================================
// Causal GQA flash attention, transposed-score formulation.
// grid (S/128, NH, B), 512 thr = 8 waves x 16 q-rows; key tile 64.
// 2 blocks/CU (54 KB LDS) -> 16 waves/CU. Wave-level causal skip for
// fully-masked key tiles. S^T = K@Q^T (softmax rows on lane&15);
// P^T written as 8B packs; PV reads b128. Q frags in registers.
// ==========================================================================
__global__ __launch_bounds__(512, 2) void attn_kernel(const u16* __restrict__ QKV,
                                                      const u16* __restrict__ Vt,
                                                      u16* __restrict__ O) {
    __shared__ __align__(16) u16 Ks[64 * 136];   // [key][d]  pad 136
    __shared__ __align__(16) u16 Vs[128 * 72];   // [d][key]  pad 72
    __shared__ __align__(16) u16 Ps[128 * 72];   // [qrow][key] pad 72
    const int tid = threadIdx.x;
    const int wave = tid >> 6, lane = tid & 63;
    const int lr = lane & 15, lq = lane >> 4;
    const int qt = 15 - blockIdx.x;  // heavy tiles dispatch first
    const int h = blockIdx.y, b = blockIdx.z;
    const int kv = h >> 1;
    const int q0 = qt * 128;
    const int wq = wave * 16;

    // Q fragments in registers (B-operand: n=qrow on lr, k=d on lq*8+j)
    short8 qf[4];
#pragma unroll
    for (int t = 0; t < 4; t++)
        qf[t] = *(const short8*)(QKV + (size_t)(b * 2048 + q0 + wq + lr) * 4096 + h * 128 + t * 32 + lq * 8);

    floatx4 zf = {0.f, 0.f, 0.f, 0.f};
    floatx4 oacc[8];
#pragma unroll
    for (int jn = 0; jn < 8; jn++) oacc[jn] = zf;
    float mstate = -1e30f;
    float lstate = 0.f;

    const int nIter = (qt + 1) * 2;
    for (int kt = 0; kt < nIter; kt++) {
        const int k0 = kt * 64;
        __syncthreads();  // prev iter done reading Ks/Vs
        {
            // Ks: 64 keys x 128 d -> 1024 int4; Vs: 128 d x 64 keys -> 1024 int4
            int4 rk[2], rv[2];
#pragma unroll
            for (int r = 0; r < 2; r++) {
                int idx = r * 512 + tid;  // 0..1023
                rk[r] = *(const int4*)(QKV + (size_t)(b * 2048 + k0 + (idx >> 4)) * 4096 + 2048 + kv * 128 + ((idx & 15) << 3));
                rv[r] = *(const int4*)(Vt + (size_t)((b * 8 + kv) * 128 + (idx >> 3)) * 2048 + k0 + ((idx & 7) << 3));
            }
#pragma unroll
            for (int r = 0; r < 2; r++) {
                int idx = r * 512 + tid;
                *(int4*)(Ks + (idx >> 4) * 136 + ((idx & 15) << 3)) = rk[r];
                *(int4*)(Vs + (idx >> 3) * 72 + ((idx & 7) << 3)) = rv[r];
            }
        }
        __syncthreads();

        // wave-level causal skip: this wave's 16 q-rows all < k0 -> zero tile
        if (k0 <= q0 + wq + 15) {
            // S^T = K @ Q^T : sacc[jm]; key = jm*16+lq*4+r, qrow = lr
            floatx4 sacc[4];
#pragma unroll
            for (int jm = 0; jm < 4; jm++) sacc[jm] = zf;
#pragma unroll
            for (int t = 0; t < 4; t++) {
                short8 a[4];
#pragma unroll
                for (int jm = 0; jm < 4; jm++)
                    a[jm] = *(const short8*)(Ks + (jm * 16 + lr) * 136 + t * 32 + lq * 8);
#pragma unroll
                for (int jm = 0; jm < 4; jm++)
                    sacc[jm] = __builtin_amdgcn_mfma_f32_16x16x32_bf16(a[jm], qf[t], sacc[jm], 0, 0, 0);
            }

            // causal mask (wave-uniform branch)
            if (k0 + 63 > q0 + wq) {
#pragma unroll
                for (int jm = 0; jm < 4; jm++) {
                    int diff = (q0 + wq + lr) - (k0 + jm * 16 + lq * 4);
#pragma unroll
                    for (int r = 0; r < 4; r++)
                        if (r > diff) sacc[jm][r] = -1e30f;
                }
            }

            // online softmax per qrow (qrow on lane&15; reduce across quads)
            float mx = -1e30f;
#pragma unroll
            for (int jm = 0; jm < 4; jm++)
#pragma unroll
                for (int r = 0; r < 4; r++) mx = fmaxf(mx, sacc[jm][r]);
            mx = fmaxf(mx, __shfl_xor(mx, 16));
            mx = fmaxf(mx, __shfl_xor(mx, 32));
            float mnew = fmaxf(mstate, mx);
            float alpha = exp2f(mstate - mnew);
            mstate = mnew;
            float rs = 0.f;
#pragma unroll
            for (int jm = 0; jm < 4; jm++)
#pragma unroll
                for (int r = 0; r < 4; r++) {
                    float p = exp2f(sacc[jm][r] - mnew);
                    sacc[jm][r] = p;
                    rs += p;
                }
            rs += __shfl_xor(rs, 16);
            rs += __shfl_xor(rs, 32);
            lstate = lstate * alpha + rs;

            // P^T -> Ps[qrow][key]: lane packs 4 consecutive keys = 8B write
#pragma unroll
            for (int jm = 0; jm < 4; jm++) {
                u16 o[4] = {f2bf(sacc[jm][0]), f2bf(sacc[jm][1]),
                            f2bf(sacc[jm][2]), f2bf(sacc[jm][3])};
                *(u64*)(Ps + (wq + lr) * 72 + jm * 16 + lq * 4) = *(u64*)o;
            }

            // rescale O: alpha at qrow=lr; oacc rows at qrow=lq*4+r
            float ao[4];
#pragma unroll
            for (int r = 0; r < 4; r++) ao[r] = __shfl(alpha, lq * 4 + r);
#pragma unroll
            for (int jn = 0; jn < 8; jn++)
#pragma unroll
                for (int r = 0; r < 4; r++) oacc[jn][r] *= ao[r];

            // O += P @ V (A=P rows wq.., B=V d-rows; both b128)
#pragma unroll
            for (int t = 0; t < 2; t++) {
                short8 pa, vb[8];
                pa = *(const short8*)(Ps + (wq + lr) * 72 + t * 32 + lq * 8);
#pragma unroll
                for (int jn = 0; jn < 8; jn++)
                    vb[jn] = *(const short8*)(Vs + (jn * 16 + lr) * 72 + t * 32 + lq * 8);
#pragma unroll
                for (int jn = 0; jn < 8; jn++)
                    oacc[jn] = __builtin_amdgcn_mfma_f32_16x16x32_bf16(pa, vb[jn], oacc[jn], 0, 0, 0);
            }
        }
    }

    // epilogue: O / l   (l at qrow=lr -> transpose to qrow=lq*4+r)
    float lo[4];
#pragma unroll
    for (int r = 0; r < 4; r++) lo[r] = __shfl(lstate, lq * 4 + r);
#pragma unroll
    for (int jn = 0; jn < 8; jn++)
#pragma unroll
        for (int r = 0; r < 4; r++) {
            int row = q0 + wq + lq * 4 + r;
            O[(size_t)(b * 2048 + row) * 2048 + h * 128 + jn * 16 + lr] =
                f2bf(oacc[jn][r] / lo[r]);
        }
}

// ==========================================================================
extern "C" void kernel_launch(void* const* d_in, const int* in_sizes, int n_in,
                              void* d_out, int out_size, void* d_ws, size_t ws_size,
                              hipStream_t stream) {
    const float* X = (const float*)d_in[0];
    const float* cosb = (const float*)d_in[1];
    const float* sinb = (const float*)d_in[2];
    const float* Wq = (const float*)d_in[3];
    const float* Wk = (const float*)d_in[4];
    const float* Wv = (const float*)d_in[5];
    const float* Wo = (const float*)d_in[6];
    const float* qw = (const float*)d_in[7];
    const float* kw = (const float*)d_in[8];
    float* out = (float*)d_out;
    u16* ws = (u16*)d_ws;

    u16* WqkvT = ws;                    // 4096x2048 = 8388608
    u16* WoT = WqkvT + 8388608;         // 4194304
    u16* Xb = WoT + 4194304;            // 8388608 (dead after QKV GEMM)
    u16* QKVb = Xb + 8388608;           // 4096x4096 = 16777216
    u16* Vtb = QKVb + 16777216;         // 4194304
    u16* Ob = Xb;                       // alias
    // total 41,943,040 u16 = 83.9 MB

    dim3 tb(32, 32);
    transpose_wc<<<dim3(64, 64), tb, 0, stream>>>(Wq, WqkvT, 2048, 2048);
    transpose_wc<<<dim3(32, 64), tb, 0, stream>>>(Wk, WqkvT + 2048 * 2048, 2048, 1024);
    transpose_wc<<<dim3(32, 64), tb, 0, stream>>>(Wv, WqkvT + 3072 * 2048, 2048, 1024);
    transpose_wc<<<dim3(64, 64), tb, 0, stream>>>(Wo, WoT, 2048, 2048);
    convert_x<<<8192, 256, 0, stream>>>(X, Xb);

    gemm_bt<u16><<<dim3(32, 32), 256, 0, stream>>>(Xb, WqkvT, QKVb, 4096, 4096, 2048);

    norm_rope<<<24576, 256, 0, stream>>>(QKVb, cosb, sinb, qw, kw);
    transpose_v<<<dim3(64, 4, 16), tb, 0, stream>>>(QKVb, Vtb);

    attn_kernel<<<dim3(16, 16, 2), 512, 0, stream>>>(QKVb, Vtb, Ob);

    gemm_bt<float><<<dim3(16, 32), 256, 0, stream>>>(Ob, WoT, out, 4096, 2048, 2048);
}